// Round 8
// baseline (3275.265 us; speedup 1.0000x reference)
//
#include <hip/hip_runtime.h>
#include <math.h>

#define NN_ 128   // batch
#define TT  100   // time steps
#define SS  128   // state dim
#define AA  32    // action dim
#define LL  1024  // hidden (= Z)
#define NBLK 264  // 4 groups x (64 matmul + 2 head)
#define GBLK 66   // blocks per group
#define HRS  1034 // LDS h-stage row stride: bank=(5m+4q)%32, max 2-way (free)

typedef __attribute__((ext_vector_type(8))) short bf16x8;   // 8 bf16 in 4 VGPRs
typedef __attribute__((ext_vector_type(4))) float f32x4;

__device__ __forceinline__ float sigmoidf_(float x) { return 1.0f / (1.0f + expf(-x)); }
__device__ __forceinline__ unsigned short f2bf(float x) {
    union { float f; unsigned u; } v; v.f = x;
    return (unsigned short)((v.u + 0x7fffu + ((v.u >> 16) & 1u)) >> 16);   // RNE
}

// ---- agent-scope (LLC-coherent, L2-bypassing) access helpers
__device__ __forceinline__ bf16x8 lda16(const unsigned short* p) {   // 16B via 2x8B agent loads
    union { bf16x8 v; unsigned long long q[2]; } u;
    u.q[0] = __hip_atomic_load((const unsigned long long*)p,     __ATOMIC_RELAXED, __HIP_MEMORY_SCOPE_AGENT);
    u.q[1] = __hip_atomic_load((const unsigned long long*)p + 1, __ATOMIC_RELAXED, __HIP_MEMORY_SCOPE_AGENT);
    return u.v;
}
__device__ __forceinline__ void sta2(unsigned short* p, unsigned short v) {
    __hip_atomic_store(p, v, __ATOMIC_RELAXED, __HIP_MEMORY_SCOPE_AGENT);
}

struct PParams {
    const float *s, *a, *s_next, *eps;
    const float *eWih, *eWhh, *ebih, *ebhh;
    const float *muW, *mub, *lvW, *lvb;
    const float *dWih, *dWhh, *dbih, *dbhh;
    const float *d1W, *d1b, *d2W, *d2b, *d3W, *d3b;
    int *bar;
    int *endv, *startv, *limitv;
    unsigned short *hencAb, *hencBb, *hdecAb, *hdecBb, *hf_bf;
    unsigned short *eWih_b, *eWhh_b, *dWih_b, *dWhh_b, *mlW_b, *xenc_b, *adec_b;
    unsigned short *d1Wb, *d2Wb, *d3Wb;
    float *loss;
};

// ---------------------------------------------------------------- LLC->LDS h-tile stages
// 32 rows x 1024 cols bf16 (64 KB): 4096 16B chunks over 256 threads, 2 batches of 8.
__device__ __forceinline__ void stage_h32(const unsigned short* __restrict__ src, int n0,
                                          unsigned short* hstage, int tid) {
    #pragma unroll
    for (int b = 0; b < 2; ++b) {
        bf16x8 v[8];
        #pragma unroll
        for (int k = 0; k < 8; ++k) {
            const int ci = tid + ((b * 8 + k) << 8);
            v[k] = lda16(src + (size_t)(n0 + (ci >> 7)) * LL + (ci & 127) * 8);
        }
        #pragma unroll
        for (int k = 0; k < 8; ++k) {
            const int ci = tid + ((b * 8 + k) << 8);
            *(bf16x8*)&hstage[(ci >> 7) * HRS + (ci & 127) * 8] = v[k];
        }
    }
}
// 16 rows (head blocks): 2048 chunks, 8 per thread.
__device__ __forceinline__ void stage_h16(const unsigned short* __restrict__ src, int n0,
                                          unsigned short* hstage, int tid) {
    bf16x8 v[8];
    #pragma unroll
    for (int k = 0; k < 8; ++k) {
        const int ci = tid + (k << 8);
        v[k] = lda16(src + (size_t)(n0 + (ci >> 7)) * LL + (ci & 127) * 8);
    }
    #pragma unroll
    for (int k = 0; k < 8; ++k) {
        const int ci = tid + (k << 8);
        *(bf16x8*)&hstage[(ci >> 7) * HRS + (ci & 127) * 8] = v[k];
    }
}

// ---------------------------------------------------------------- barriers
// Global (gen 1 only): bar[g*16] 8 counters; bar[128] master; bar[132] broken; bar[144+b*16] flags.
__device__ void gbar_global(int* bar, int bid, int tid, int gen) {
    __syncthreads();
    if (tid == 0) {
        if (__hip_atomic_load(bar + 132, __ATOMIC_RELAXED, __HIP_MEMORY_SCOPE_AGENT) == 0) {
            const int g = bid & 7;
            int pos = __hip_atomic_fetch_add(bar + g * 16, 1, __ATOMIC_RELAXED, __HIP_MEMORY_SCOPE_AGENT);
            if (pos + 1 == (NBLK / 8) * gen) {
                int mp = __hip_atomic_fetch_add(bar + 128, 1, __ATOMIC_RELAXED, __HIP_MEMORY_SCOPE_AGENT);
                if (mp + 1 == 8 * gen) {
                    for (int b = 0; b < NBLK; ++b)
                        __hip_atomic_store(bar + 144 + b * 16, gen, __ATOMIC_RELAXED, __HIP_MEMORY_SCOPE_AGENT);
                }
            }
            int it = 0;
            while (__hip_atomic_load(bar + 144 + bid * 16, __ATOMIC_RELAXED, __HIP_MEMORY_SCOPE_AGENT) < gen) {
                __builtin_amdgcn_s_sleep(1);
                if (++it > 4000000) {
                    __hip_atomic_store(bar + 132, 1, __ATOMIC_RELAXED, __HIP_MEMORY_SCOPE_AGENT);
                    break;
                }
            }
        }
    }
    __syncthreads();
}
// Group-local: gb[0],gb[8] 2 sub-counters (33 each); gb[16] master; gb[24] flag. Monotone, gen from 1.
__device__ void gbar_group(int* gb, int* broken, int lbid, int tid, int gen) {
    __syncthreads();   // also drains each wave's sc1 stores (vmcnt(0) before s_barrier)
    if (tid == 0) {
        if (__hip_atomic_load(broken, __ATOMIC_RELAXED, __HIP_MEMORY_SCOPE_AGENT) == 0) {
            int* cnt = gb + ((lbid & 1) << 3);
            int pos = __hip_atomic_fetch_add(cnt, 1, __ATOMIC_RELAXED, __HIP_MEMORY_SCOPE_AGENT);
            if (pos + 1 == (GBLK / 2) * gen) {
                int mp = __hip_atomic_fetch_add(gb + 16, 1, __ATOMIC_RELAXED, __HIP_MEMORY_SCOPE_AGENT);
                if (mp + 1 == 2 * gen)
                    __hip_atomic_store(gb + 24, gen, __ATOMIC_RELAXED, __HIP_MEMORY_SCOPE_AGENT);
            }
            int it = 0;
            while (__hip_atomic_load(gb + 24, __ATOMIC_RELAXED, __HIP_MEMORY_SCOPE_AGENT) < gen) {
                __builtin_amdgcn_s_sleep(1);
                if (++it > 4000000) {
                    __hip_atomic_store(broken, 1, __ATOMIC_RELAXED, __HIP_MEMORY_SCOPE_AGENT);
                    break;
                }
            }
        }
    }
    __syncthreads();
}

// ---------------------------------------------------------------- init (separate launch)
__global__ void init_kernel(int* bar, float* loss) {
    for (int i = threadIdx.x; i < 5120; i += 256) bar[i] = 0;
    if (threadIdx.x == 0) loss[0] = 0.0f;
}

// ---------------------------------------------------------------- GRU step matmul tile
// Group decomposition: 64 matmul blocks x 16 j-cols (all 3 gates), 32 samples.
// Waves: nh = w&1 (16-sample half), kh = w>>1 (K-half, split-K via LDS red).
template<int XK, bool IS_DEC>
__device__ void gru_tile(const int ng0, const int jb, const int tid,
    const unsigned short* __restrict__ h_bf, unsigned short* __restrict__ ho_bf,
    const unsigned short* __restrict__ Whh_b, const unsigned short* __restrict__ Wih_b,
    const unsigned short* __restrict__ x_bf,
    const float* __restrict__ bih, const float* __restrict__ bhh,
    const int* __restrict__ endv, unsigned short* __restrict__ hf_bf,
    int t, f32x4 (&red)[2][4][64], unsigned short* hstage, f32x4& hold)
{
    const int lane = tid & 63, w = tid >> 6;
    const int nh = w & 1, kh = w >> 1;
    const int m = lane & 15, quad = lane >> 4;
    const int jcol = jb + m;

    stage_h32(h_bf, ng0, hstage, tid);
    __syncthreads();

    f32x4 accr{}, accz{}, acchn{}, accxn{};

    {   // hidden: K = 1024, 32 chunks, split 16/16 across kh; A from LDS
        const int arow = (nh * 16 + m) * HRS + quad * 8;
        const unsigned short* brp = Whh_b + (size_t)(0 * LL + jcol) * LL + quad * 8;
        const unsigned short* bzp = Whh_b + (size_t)(1 * LL + jcol) * LL + quad * 8;
        const unsigned short* bnp = Whh_b + (size_t)(2 * LL + jcol) * LL + quad * 8;
        #pragma unroll 4
        for (int c = kh * 16; c < kh * 16 + 16; ++c) {
            const int k0 = c * 32;
            bf16x8 av = *(const bf16x8*)&hstage[arow + k0];
            bf16x8 br = *(const bf16x8*)(brp + k0);
            bf16x8 bz = *(const bf16x8*)(bzp + k0);
            bf16x8 bn = *(const bf16x8*)(bnp + k0);
            accr  = __builtin_amdgcn_mfma_f32_16x16x32_bf16(av, br, accr, 0, 0, 0);
            accz  = __builtin_amdgcn_mfma_f32_16x16x32_bf16(av, bz, accz, 0, 0, 0);
            acchn = __builtin_amdgcn_mfma_f32_16x16x32_bf16(av, bn, acchn, 0, 0, 0);
        }
    }
    {   // input: K = XK (enc 160, dec 32); read-only -> plain L2-cached loads
        const int XC = XK / 32, XC0 = (XC + 1) / 2;
        const size_t xstride = IS_DEC ? (size_t)(50 * AA) : (size_t)(TT * (SS + AA));
        const unsigned short* xp  = x_bf + (size_t)(ng0 + nh * 16 + m) * xstride + (size_t)t * XK + quad * 8;
        const unsigned short* brp = Wih_b + (size_t)(0 * LL + jcol) * XK + quad * 8;
        const unsigned short* bzp = Wih_b + (size_t)(1 * LL + jcol) * XK + quad * 8;
        const unsigned short* bnp = Wih_b + (size_t)(2 * LL + jcol) * XK + quad * 8;
        #pragma unroll
        for (int c = (kh ? XC0 : 0); c < (kh ? XC : XC0); ++c) {
            const int k0 = c * 32;
            bf16x8 av = *(const bf16x8*)(xp + k0);
            bf16x8 br = *(const bf16x8*)(brp + k0);
            bf16x8 bz = *(const bf16x8*)(bzp + k0);
            bf16x8 bn = *(const bf16x8*)(bnp + k0);
            accr  = __builtin_amdgcn_mfma_f32_16x16x32_bf16(av, br, accr, 0, 0, 0);
            accz  = __builtin_amdgcn_mfma_f32_16x16x32_bf16(av, bz, accz, 0, 0, 0);
            accxn = __builtin_amdgcn_mfma_f32_16x16x32_bf16(av, bn, accxn, 0, 0, 0);
        }
    }
    if (kh == 1) {
        red[nh][0][lane] = accr;  red[nh][1][lane] = accz;
        red[nh][2][lane] = acchn; red[nh][3][lane] = accxn;
    }
    __syncthreads();
    if (kh == 0) {
        accr  += red[nh][0][lane];  accz  += red[nh][1][lane];
        acchn += red[nh][2][lane];  accxn += red[nh][3][lane];
        const float br_  = bih[jcol] + bhh[jcol];
        const float bz_  = bih[LL + jcol] + bhh[LL + jcol];
        const float bxn_ = bih[2 * LL + jcol];
        const float bhn_ = bhh[2 * LL + jcol];
        #pragma unroll
        for (int i = 0; i < 4; ++i) {
            const int n = ng0 + nh * 16 + quad * 4 + i;   // C layout: row=quad*4+i, col=m
            float r = sigmoidf_(accr[i] + br_);
            float z = sigmoidf_(accz[i] + bz_);
            float g = tanhf(accxn[i] + bxn_ + r * (acchn[i] + bhn_));
            float hn = (1.0f - z) * g + z * hold[i];
            hold[i] = hn;
            sta2(ho_bf + (size_t)n * LL + jcol, f2bf(hn));
            if (!IS_DEC) { if (endv[n] == t) sta2(hf_bf + (size_t)n * LL + jcol, f2bf(hn)); }
        }
    }
}

// ---------------------------------------------------------------- reparametrize tile -> hold regs + bf16
__device__ void emb_tile(const PParams& P, const int ng0, const int jb, const int tid,
                         f32x4 (&red)[2][4][64], unsigned short* hstage, f32x4& hold)
{
    const int lane = tid & 63, w = tid >> 6;
    const int nh = w & 1, kh = w >> 1;
    const int m = lane & 15, quad = lane >> 4;
    const int jcol = jb + m;

    stage_h32(P.hf_bf, ng0, hstage, tid);
    __syncthreads();

    f32x4 accm{}, accl{};
    const int arow = (nh * 16 + m) * HRS + quad * 8;
    const unsigned short* bmp = P.mlW_b + (size_t)jcol * LL + quad * 8;
    const unsigned short* blp = P.mlW_b + (size_t)(LL + jcol) * LL + quad * 8;
    #pragma unroll 4
    for (int c = kh * 16; c < kh * 16 + 16; ++c) {
        const int k0 = c * 32;
        bf16x8 av = *(const bf16x8*)&hstage[arow + k0];
        bf16x8 bm = *(const bf16x8*)(bmp + k0);
        bf16x8 bl = *(const bf16x8*)(blp + k0);
        accm = __builtin_amdgcn_mfma_f32_16x16x32_bf16(av, bm, accm, 0, 0, 0);
        accl = __builtin_amdgcn_mfma_f32_16x16x32_bf16(av, bl, accl, 0, 0, 0);
    }
    if (kh == 1) { red[nh][0][lane] = accm; red[nh][1][lane] = accl; }
    __syncthreads();
    if (kh == 0) {
        accm += red[nh][0][lane]; accl += red[nh][1][lane];
        #pragma unroll
        for (int i = 0; i < 4; ++i) {
            const int n = ng0 + nh * 16 + quad * 4 + i;
            float mu = accm[i] + P.mub[jcol];
            float lv = accl[i] + P.lvb[jcol];
            float e = mu + expf(0.5f * lv) * P.eps[(size_t)n * LL + jcol];
            hold[i] = e;
            sta2(P.hdecAb + (size_t)n * LL + jcol, f2bf(e));
        }
    }
}

// ---------------------------------------------------------------- MFMA decoder head: 16 samples/block
__device__ void head_tile(const PParams& P, const int n0, const int tid,
                          const unsigned short* __restrict__ h_bf, int ti,
                          unsigned short* hstage, char* shu)
{
    auto& ylds  = *(unsigned short (*)[16][136])(shu);
    auto& y2lds = *(unsigned short (*)[16][72])(shu + 4352);
    float* lred = (float*)(shu + 4352 + 2304);
    const int lane = tid & 63, w = tid >> 6;
    const int m16 = lane & 15, quad = lane >> 4;

    stage_h16(h_bf, n0, hstage, tid);
    __syncthreads();

    // ---- y1: K=1024, 8 j-tiles, wave w -> {2w, 2w+1}
    #pragma unroll
    for (int jt = 0; jt < 2; ++jt) {
        const int c0 = (w * 2 + jt) * 16;
        f32x4 acc{};
        const int abase = m16 * HRS + quad * 8;
        const unsigned short* bp = P.d1Wb + (size_t)(c0 + m16) * LL + quad * 8;
        #pragma unroll 4
        for (int c = 0; c < 32; ++c) {
            bf16x8 av = *(const bf16x8*)&hstage[abase + c * 32];
            bf16x8 bv = *(const bf16x8*)(bp + c * 32);
            acc = __builtin_amdgcn_mfma_f32_16x16x32_bf16(av, bv, acc, 0, 0, 0);
        }
        const float b = P.d1b[c0 + m16];
        #pragma unroll
        for (int i = 0; i < 4; ++i)
            ylds[quad * 4 + i][c0 + m16] = f2bf(fmaxf(acc[i] + b, 0.0f));
    }
    __syncthreads();

    // ---- y2: K=128, wave w -> tile w
    {
        const int c0 = w * 16;
        f32x4 acc{};
        #pragma unroll
        for (int c = 0; c < 4; ++c) {
            bf16x8 av = *(const bf16x8*)&ylds[m16][c * 32 + quad * 8];
            bf16x8 bv = *(const bf16x8*)(P.d2Wb + (size_t)(c0 + m16) * 128 + c * 32 + quad * 8);
            acc = __builtin_amdgcn_mfma_f32_16x16x32_bf16(av, bv, acc, 0, 0, 0);
        }
        const float b = P.d2b[c0 + m16];
        #pragma unroll
        for (int i = 0; i < 4; ++i)
            y2lds[quad * 4 + i][c0 + m16] = f2bf(fmaxf(acc[i] + b, 0.0f));
    }
    __syncthreads();

    // ---- y3: K=64, wave w -> {2w, 2w+1}; fused masked L1
    float lsum = 0.0f;
    #pragma unroll
    for (int jt = 0; jt < 2; ++jt) {
        const int c0 = (w * 2 + jt) * 16;
        f32x4 acc{};
        #pragma unroll
        for (int c = 0; c < 2; ++c) {
            bf16x8 av = *(const bf16x8*)&y2lds[m16][c * 32 + quad * 8];
            bf16x8 bv = *(const bf16x8*)(P.d3Wb + (size_t)(c0 + m16) * 64 + c * 32 + quad * 8);
            acc = __builtin_amdgcn_mfma_f32_16x16x32_bf16(av, bv, acc, 0, 0, 0);
        }
        const int col = c0 + m16;
        const float b = P.d3b[col];
        #pragma unroll
        for (int i = 0; i < 4; ++i) {
            const int n = n0 + quad * 4 + i;
            if (ti < P.limitv[n]) {
                int tr = ti + P.startv[n]; if (tr >= TT) tr -= TT;
                float v = P.s_next[(size_t)n * TT * SS + (size_t)tr * SS + col];
                lsum += fabsf(v - (acc[i] + b));
            }
        }
    }
    for (int off = 32; off >= 1; off >>= 1) lsum += __shfl_down(lsum, off);
    if (lane == 0) lred[w] = lsum;
    __syncthreads();
    if (tid == 0) atomicAdd(P.loss, lred[0] + lred[1] + lred[2] + lred[3]);
}

// ---------------------------------------------------------------- the persistent kernel
__global__ __launch_bounds__(256, 2)
void persist(PParams P)
{
    __shared__ __align__(16) unsigned short hstage[32 * HRS];   // 66176 B
    __shared__ __align__(16) char shu[8192];                    // red OR head ylds/y2lds/lred
    __shared__ int mint, sME, sML;
    f32x4 (&red)[2][4][64] = *(f32x4 (*)[2][4][64])(shu);
    const int bid = blockIdx.x, tid = threadIdx.x;
    const int g = bid / GBLK, lbid = bid - g * GBLK;
    const int ng0 = g * 32;                   // group's first sample
    const int jb  = lbid * 16;                // matmul blocks only (lbid < 64)
    int* gb = P.bar + 4608 + g * 32;          // group barrier state
    int* broken = P.bar + 132;

    // ================= phase 0: cast (plain stores), split detection, h0, adec
    {
        const long N0 = 3072L * 160, N1 = N0 + 3072L * 1024, N2 = N1 + 3072L * 32,
                   N3 = N2 + 3072L * 1024, N4 = N3 + 1048576L, N5 = N4 + 1048576L,
                   N6 = N5 + 128L * 100 * 160, N7 = N6 + 131072L, N8 = N7 + 8192L,
                   N9 = N8 + 8192L;
        for (long i = (long)bid * 256 + tid; i < N9; i += (long)NBLK * 256) {
            if (i < N0)      P.eWih_b[i]      = f2bf(P.eWih[i]);
            else if (i < N1) P.eWhh_b[i - N0] = f2bf(P.eWhh[i - N0]);
            else if (i < N2) P.dWih_b[i - N1] = f2bf(P.dWih[i - N1]);
            else if (i < N3) P.dWhh_b[i - N2] = f2bf(P.dWhh[i - N2]);
            else if (i < N4) P.mlW_b[i - N3]  = f2bf(P.muW[i - N3]);
            else if (i < N5) P.mlW_b[1048576L + (i - N4)] = f2bf(P.lvW[i - N4]);
            else if (i < N6) {
                long j = i - N5;                  // n*16000 + t*160 + k
                int  k = (int)(j % 160);
                long nt = j / 160;
                int  t = (int)(nt % 100), n = (int)(nt / 100);
                float v = (k < SS) ? P.s[(size_t)n * TT * SS + (size_t)t * SS + k]
                                   : P.a[(size_t)n * TT * AA + (size_t)t * AA + (k - SS)];
                P.xenc_b[j] = f2bf(v);
            }
            else if (i < N7) P.d1Wb[i - N6] = f2bf(P.d1W[i - N6]);
            else if (i < N8) P.d2Wb[i - N7] = f2bf(P.d2W[i - N7]);
            else             P.d3Wb[i - N8] = f2bf(P.d3W[i - N8]);
        }
    }
    if (bid < NN_) {
        const int n = bid;
        if (tid == 0) mint = TT - 1;
        __syncthreads();
        int t = tid + 1;
        if (t < TT && tid < 128) {
            const float* row = P.s + (size_t)n * TT * SS + (size_t)t * SS;
            bool allz = true;
            for (int i = 0; i < SS; ++i) { if (row[i] != 0.0f) { allz = false; break; } }
            if (allz) atomicMin(&mint, t);
        }
        __syncthreads();
        const int m = mint, st = m + 1;
        if (tid == 0) { P.endv[n] = m - 1; P.startv[n] = st; P.limitv[n] = TT - 1 - m; }
        for (int idx = tid; idx < LL; idx += 256)
            P.hencAb[(size_t)n * LL + idx] = 0x3F80;   // bf16 1.0
        for (int idx = tid; idx < 50 * AA; idx += 256) {
            int i = idx >> 5, k = idx & 31;
            int tr = i + st; if (tr >= TT) tr -= TT;
            P.adec_b[(size_t)n * (50 * AA) + idx] =
                f2bf(P.a[(size_t)n * TT * AA + (size_t)tr * AA + k]);
        }
    }
    // one-time global heavy barrier: flush phase-0 plain stores, drop stale lines
    __syncthreads();
    if (tid == 0) __threadfence();
    gbar_global(P.bar, bid, tid, 1);
    if (tid == 0) __threadfence();
    __syncthreads();

    // ================= group-local ME = max(end), ML = max(limit) over 32 samples
    int ME, ML;
    {
        int lv = 0, ev = 0;
        if (tid < 32) { lv = P.limitv[ng0 + tid]; ev = P.endv[ng0 + tid]; }
        if (tid < 64) {
            for (int off = 16; off >= 1; off >>= 1) {
                lv = max(lv, __shfl_down(lv, off));
                ev = max(ev, __shfl_down(ev, off));
            }
            if (tid == 0) { sML = lv; sME = ev; }
        }
        __syncthreads();
        ML = sML; ME = sME;
        __syncthreads();
    }

    f32x4 hold = { 1.0f, 1.0f, 1.0f, 1.0f };   // enc h0 = ones (fp32 state lives here)
    int ggen = 0;

    // ================= encoder: t = 0..ME_g
    for (int t = 0; t <= ME; ++t) {
        if (lbid < 64) {
            const unsigned short* hib = (t & 1) ? P.hencBb : P.hencAb;
            unsigned short*       hob = (t & 1) ? P.hencAb : P.hencBb;
            gru_tile<160, false>(ng0, jb, tid, hib, hob,
                                 P.eWhh_b, P.eWih_b, P.xenc_b, P.ebih, P.ebhh,
                                 P.endv, P.hf_bf, t, red, hstage, hold);
        }
        gbar_group(gb, broken, lbid, tid, ++ggen);
    }

    // ================= reparametrize (deposits decoder h0 into hold regs)
    if (lbid < 64) emb_tile(P, ng0, jb, tid, red, hstage, hold);
    gbar_group(gb, broken, lbid, tid, ++ggen);

    // ================= decoder: i = 0..ML_g; matmul (i<ML) overlaps head for step i-1
    for (int i = 0; i <= ML; ++i) {
        const unsigned short* hib = (i & 1) ? P.hdecBb : P.hdecAb;
        if (lbid < 64) {
            if (i < ML) {
                unsigned short* hob = (i & 1) ? P.hdecAb : P.hdecBb;
                gru_tile<32, true>(ng0, jb, tid, hib, hob,
                                   P.dWhh_b, P.dWih_b, P.adec_b, P.dbih, P.dbhh,
                                   nullptr, nullptr, i, red, hstage, hold);
            }
        } else if (i >= 1) {
            head_tile(P, ng0 + (lbid - 64) * 16, tid, hib, i - 1, hstage, shu);
        }
        gbar_group(gb, broken, lbid, tid, ++ggen);
    }
}

// ---------------------------------------------------------------- launch
extern "C" void kernel_launch(void* const* d_in, const int* in_sizes, int n_in,
                              void* d_out, int out_size, void* d_ws, size_t ws_size,
                              hipStream_t stream) {
    PParams P;
    P.s      = (const float*)d_in[0];
    P.a      = (const float*)d_in[1];
    P.s_next = (const float*)d_in[3];
    P.eps    = (const float*)d_in[4];
    P.eWih   = (const float*)d_in[5];
    P.eWhh   = (const float*)d_in[6];
    P.ebih   = (const float*)d_in[7];
    P.ebhh   = (const float*)d_in[8];
    P.muW    = (const float*)d_in[9];
    P.mub    = (const float*)d_in[10];
    P.lvW    = (const float*)d_in[11];
    P.lvb    = (const float*)d_in[12];
    // st1..st3 (13..18) dead code w.r.t. the loss
    P.dWih   = (const float*)d_in[19];
    P.dWhh   = (const float*)d_in[20];
    P.dbih   = (const float*)d_in[21];
    P.dbhh   = (const float*)d_in[22];
    P.d1W    = (const float*)d_in[23];
    P.d1b    = (const float*)d_in[24];
    P.d2W    = (const float*)d_in[25];
    P.d2b    = (const float*)d_in[26];
    P.d3W    = (const float*)d_in[27];
    P.d3b    = (const float*)d_in[28];
    P.loss   = (float*)d_out;

    char* p = (char*)d_ws;
    P.bar    = (int*)p;                    p += 20480;
    P.endv   = (int*)p;                    p += 512;
    P.startv = (int*)p;                    p += 512;
    P.limitv = (int*)p;                    p += 512;
    p += 2560;                             // pad
    P.hencAb = (unsigned short*)p;         p += 128 * 1024 * 2;
    P.hencBb = (unsigned short*)p;         p += 128 * 1024 * 2;
    P.hdecAb = (unsigned short*)p;         p += 128 * 1024 * 2;
    P.hdecBb = (unsigned short*)p;         p += 128 * 1024 * 2;
    P.hf_bf  = (unsigned short*)p;         p += 128 * 1024 * 2;
    P.eWih_b = (unsigned short*)p;         p += 3072 * 160 * 2;
    P.eWhh_b = (unsigned short*)p;         p += 3072 * 1024 * 2;
    P.dWih_b = (unsigned short*)p;         p += 3072 * 32 * 2;
    P.dWhh_b = (unsigned short*)p;         p += 3072 * 1024 * 2;
    P.mlW_b  = (unsigned short*)p;         p += 2048 * 1024 * 2;
    P.xenc_b = (unsigned short*)p;         p += 128 * 100 * 160 * 2;
    P.adec_b = (unsigned short*)p;         p += 128 * 50 * 32 * 2;
    P.d1Wb   = (unsigned short*)p;         p += 128 * 1024 * 2;
    P.d2Wb   = (unsigned short*)p;         p += 64 * 128 * 2;
    P.d3Wb   = (unsigned short*)p;         p += 128 * 64 * 2;

    hipLaunchKernelGGL(init_kernel, dim3(1), dim3(256), 0, stream, P.bar, P.loss);
    hipLaunchKernelGGL(persist, dim3(NBLK), dim3(256), 0, stream, P);
}

// Round 9
// 2448.633 us; speedup vs baseline: 1.3376x; 1.3376x over previous
//
#include <hip/hip_runtime.h>
#include <math.h>

#define NN_ 128   // batch
#define TT  100   // time steps
#define SS  128   // state dim
#define AA  32    // action dim
#define LL  1024  // hidden (= Z)
#define NBLK 264  // 4 groups x 66; group = bid&3 -> group g owns XCDs {g, g+4}
#define GBLK 66   // blocks per group: 64 matmul (16 j-cols each) + 2 head
#define HRS  1034 // LDS h-stage row stride (bf16): max 2-way bank aliasing (free)

typedef __attribute__((ext_vector_type(8))) short bf16x8;   // 8 bf16 in 4 VGPRs
typedef __attribute__((ext_vector_type(4))) float f32x4;

__device__ __forceinline__ float sigmoidf_(float x) { return 1.0f / (1.0f + expf(-x)); }
__device__ __forceinline__ unsigned short f2bf(float x) {
    union { float f; unsigned u; } v; v.f = x;
    return (unsigned short)((v.u + 0x7fffu + ((v.u >> 16) & 1u)) >> 16);   // RNE
}

// ---- agent-scope (LLC-coherent) access helpers
__device__ __forceinline__ bf16x8 lda16(const unsigned short* p) {   // 16B via 2x8B agent loads
    union { bf16x8 v; unsigned long long q[2]; } u;
    u.q[0] = __hip_atomic_load((const unsigned long long*)p,     __ATOMIC_RELAXED, __HIP_MEMORY_SCOPE_AGENT);
    u.q[1] = __hip_atomic_load((const unsigned long long*)p + 1, __ATOMIC_RELAXED, __HIP_MEMORY_SCOPE_AGENT);
    return u.v;
}
__device__ __forceinline__ void sta16(unsigned short* p, bf16x8 v) { // 16B via 2x8B agent stores
    union { bf16x8 v; unsigned long long q[2]; } u; u.v = v;
    __hip_atomic_store((unsigned long long*)p,     u.q[0], __ATOMIC_RELAXED, __HIP_MEMORY_SCOPE_AGENT);
    __hip_atomic_store((unsigned long long*)p + 1, u.q[1], __ATOMIC_RELAXED, __HIP_MEMORY_SCOPE_AGENT);
}
__device__ __forceinline__ void sta2(unsigned short* p, unsigned short v) {
    __hip_atomic_store(p, v, __ATOMIC_RELAXED, __HIP_MEMORY_SCOPE_AGENT);
}

struct PParams {
    const float *s, *a, *s_next, *eps;
    const float *eWih, *eWhh, *ebih, *ebhh;
    const float *muW, *mub, *lvW, *lvb;
    const float *dWih, *dWhh, *dbih, *dbhh;
    const float *d1W, *d1b, *d2W, *d2b, *d3W, *d3b;
    int *bar;
    int *endv, *startv, *limitv;
    unsigned short *hencAb, *hencBb, *hdecAb, *hdecBb, *hf_bf;
    unsigned short *eWih_b, *eWhh_b, *dWih_b, *dWhh_b, *mlW_b, *xenc_b, *adec_b;
    unsigned short *d1Wb, *d2Wb, *d3Wb;
    float *loss;
};

// ---------------------------------------------------------------- LLC->LDS h-tile stages
// 32 rows x 1024 cols bf16 (64 KB): 4096 16B chunks / 256 threads = 16 loads each, one exposure.
__device__ __forceinline__ void stage_h32(const unsigned short* __restrict__ src, int n0,
                                          unsigned short* hstage, int tid) {
    bf16x8 v[16];
    #pragma unroll
    for (int k = 0; k < 16; ++k) {
        const int ci = tid + (k << 8);
        v[k] = lda16(src + (size_t)(n0 + (ci >> 7)) * LL + (ci & 127) * 8);
    }
    #pragma unroll
    for (int k = 0; k < 16; ++k) {
        const int ci = tid + (k << 8);
        *(bf16x8*)&hstage[(ci >> 7) * HRS + (ci & 127) * 8] = v[k];
    }
}
// 16 rows (head blocks)
__device__ __forceinline__ void stage_h16(const unsigned short* __restrict__ src, int n0,
                                          unsigned short* hstage, int tid) {
    bf16x8 v[8];
    #pragma unroll
    for (int k = 0; k < 8; ++k) {
        const int ci = tid + (k << 8);
        v[k] = lda16(src + (size_t)(n0 + (ci >> 7)) * LL + (ci & 127) * 8);
    }
    #pragma unroll
    for (int k = 0; k < 8; ++k) {
        const int ci = tid + (k << 8);
        *(bf16x8*)&hstage[(ci >> 7) * HRS + (ci & 127) * 8] = v[k];
    }
}

// ---------------------------------------------------------------- barriers
// Global (phase 0 only): bar[g*16] 8 counters; [128] master; [132] broken; [144+b*16] flags.
__device__ void gbar_global(int* bar, int bid, int tid, int gen) {
    __syncthreads();
    if (tid == 0) {
        if (__hip_atomic_load(bar + 132, __ATOMIC_RELAXED, __HIP_MEMORY_SCOPE_AGENT) == 0) {
            const int g = bid & 7;
            int pos = __hip_atomic_fetch_add(bar + g * 16, 1, __ATOMIC_RELAXED, __HIP_MEMORY_SCOPE_AGENT);
            if (pos + 1 == (NBLK / 8) * gen) {
                int mp = __hip_atomic_fetch_add(bar + 128, 1, __ATOMIC_RELAXED, __HIP_MEMORY_SCOPE_AGENT);
                if (mp + 1 == 8 * gen) {
                    for (int b = 0; b < NBLK; ++b)
                        __hip_atomic_store(bar + 144 + b * 16, gen, __ATOMIC_RELAXED, __HIP_MEMORY_SCOPE_AGENT);
                }
            }
            int it = 0;
            while (__hip_atomic_load(bar + 144 + bid * 16, __ATOMIC_RELAXED, __HIP_MEMORY_SCOPE_AGENT) < gen) {
                __builtin_amdgcn_s_sleep(1);
                if (++it > 4000000) {
                    __hip_atomic_store(bar + 132, 1, __ATOMIC_RELAXED, __HIP_MEMORY_SCOPE_AGENT);
                    break;
                }
            }
        }
    }
    __syncthreads();
}
// Group-local: gb[0,16,32,48] 4 sub-counters; gb[64] master; gb[80] flag. Monotone, gen from 1.
__device__ void gbar_group(int* gb, int* broken, int lbid, int tid, int gen) {
    __syncthreads();   // drains each wave's sc1 stores (vmcnt(0) before s_barrier)
    if (tid == 0) {
        if (__hip_atomic_load(broken, __ATOMIC_RELAXED, __HIP_MEMORY_SCOPE_AGENT) == 0) {
            const int s = lbid & 3;
            const int tgt = (s < 2) ? 17 : 16;   // 66 = 17+17+16+16
            int pos = __hip_atomic_fetch_add(gb + s * 16, 1, __ATOMIC_RELAXED, __HIP_MEMORY_SCOPE_AGENT);
            if (pos + 1 == tgt * gen) {
                int mp = __hip_atomic_fetch_add(gb + 64, 1, __ATOMIC_RELAXED, __HIP_MEMORY_SCOPE_AGENT);
                if (mp + 1 == 4 * gen)
                    __hip_atomic_store(gb + 80, gen, __ATOMIC_RELAXED, __HIP_MEMORY_SCOPE_AGENT);
            }
            int it = 0;
            while (__hip_atomic_load(gb + 80, __ATOMIC_RELAXED, __HIP_MEMORY_SCOPE_AGENT) < gen) {
                __builtin_amdgcn_s_sleep(1);
                if (++it > 4000000) {
                    __hip_atomic_store(broken, 1, __ATOMIC_RELAXED, __HIP_MEMORY_SCOPE_AGENT);
                    break;
                }
            }
        }
    }
    __syncthreads();
}

// ---------------------------------------------------------------- init (separate launch)
__global__ void init_kernel(int* bar, float* loss) {
    for (int i = threadIdx.x; i < 5120; i += 256) bar[i] = 0;
    if (threadIdx.x == 0) loss[0] = 0.0f;
}

// ---------------------------------------------------------------- GRU step matmul tile
// Per group: 64 blocks x 16 j-cols (3 gates), 32 samples. Waves: nh=w&1 sample-half, kh=w>>1 K-half.
// fp32 h state in `hold` regs of kh==0 waves; h stores coalesced 16B via LDS transpose.
template<int XK, bool IS_DEC>
__device__ void gru_tile(const int ng0, const int jb, const int tid,
    const unsigned short* __restrict__ h_bf, unsigned short* __restrict__ ho_bf,
    const unsigned short* __restrict__ Whh_b, const unsigned short* __restrict__ Wih_b,
    const unsigned short* __restrict__ x_bf,
    const float* __restrict__ bih, const float* __restrict__ bhh,
    const int* __restrict__ endv, unsigned short* __restrict__ hf_bf,
    int t, f32x4 (&red)[2][4][64], unsigned short* hstage, f32x4& hold)
{
    const int lane = tid & 63, w = tid >> 6;
    const int nh = w & 1, kh = w >> 1;
    const int m = lane & 15, quad = lane >> 4;
    const int jcol = jb + m;

    stage_h32(h_bf, ng0, hstage, tid);
    __syncthreads();

    f32x4 accr{}, accz{}, acchn{}, accxn{};

    {   // hidden: K = 1024, 32 chunks, split 16/16 across kh; A from LDS
        const int arow = (nh * 16 + m) * HRS + quad * 8;
        const unsigned short* brp = Whh_b + (size_t)(0 * LL + jcol) * LL + quad * 8;
        const unsigned short* bzp = Whh_b + (size_t)(1 * LL + jcol) * LL + quad * 8;
        const unsigned short* bnp = Whh_b + (size_t)(2 * LL + jcol) * LL + quad * 8;
        #pragma unroll 4
        for (int c = kh * 16; c < kh * 16 + 16; ++c) {
            const int k0 = c * 32;
            bf16x8 av = *(const bf16x8*)&hstage[arow + k0];
            bf16x8 br = *(const bf16x8*)(brp + k0);
            bf16x8 bz = *(const bf16x8*)(bzp + k0);
            bf16x8 bn = *(const bf16x8*)(bnp + k0);
            accr  = __builtin_amdgcn_mfma_f32_16x16x32_bf16(av, br, accr, 0, 0, 0);
            accz  = __builtin_amdgcn_mfma_f32_16x16x32_bf16(av, bz, accz, 0, 0, 0);
            acchn = __builtin_amdgcn_mfma_f32_16x16x32_bf16(av, bn, acchn, 0, 0, 0);
        }
    }
    {   // input: K = XK (enc 160, dec 32); read-only -> plain L2-cached loads
        const int XC = XK / 32, XC0 = (XC + 1) / 2;
        const size_t xstride = IS_DEC ? (size_t)(50 * AA) : (size_t)(TT * (SS + AA));
        const unsigned short* xp  = x_bf + (size_t)(ng0 + nh * 16 + m) * xstride + (size_t)t * XK + quad * 8;
        const unsigned short* brp = Wih_b + (size_t)(0 * LL + jcol) * XK + quad * 8;
        const unsigned short* bzp = Wih_b + (size_t)(1 * LL + jcol) * XK + quad * 8;
        const unsigned short* bnp = Wih_b + (size_t)(2 * LL + jcol) * XK + quad * 8;
        #pragma unroll
        for (int c = (kh ? XC0 : 0); c < (kh ? XC : XC0); ++c) {
            const int k0 = c * 32;
            bf16x8 av = *(const bf16x8*)(xp + k0);
            bf16x8 br = *(const bf16x8*)(brp + k0);
            bf16x8 bz = *(const bf16x8*)(bzp + k0);
            bf16x8 bn = *(const bf16x8*)(bnp + k0);
            accr  = __builtin_amdgcn_mfma_f32_16x16x32_bf16(av, br, accr, 0, 0, 0);
            accz  = __builtin_amdgcn_mfma_f32_16x16x32_bf16(av, bz, accz, 0, 0, 0);
            accxn = __builtin_amdgcn_mfma_f32_16x16x32_bf16(av, bn, accxn, 0, 0, 0);
        }
    }
    if (kh == 1) {
        red[nh][0][lane] = accr;  red[nh][1][lane] = accz;
        red[nh][2][lane] = acchn; red[nh][3][lane] = accxn;
    }
    __syncthreads();
    if (kh == 0) {
        accr  += red[nh][0][lane];  accz  += red[nh][1][lane];
        acchn += red[nh][2][lane];  accxn += red[nh][3][lane];
        const float br_  = bih[jcol] + bhh[jcol];
        const float bz_  = bih[LL + jcol] + bhh[LL + jcol];
        const float bxn_ = bih[2 * LL + jcol];
        const float bhn_ = bhh[2 * LL + jcol];
        unsigned short* tr = hstage + nh * (16 * 24);    // wave-private transpose scratch
        #pragma unroll
        for (int i = 0; i < 4; ++i) {
            const int n = ng0 + nh * 16 + quad * 4 + i;  // C layout: row=quad*4+i, col=m
            float r = sigmoidf_(accr[i] + br_);
            float z = sigmoidf_(accz[i] + bz_);
            float g = tanhf(accxn[i] + bxn_ + r * (acchn[i] + bhn_));
            float hn = (1.0f - z) * g + z * hold[i];
            hold[i] = hn;
            unsigned short hb = f2bf(hn);
            tr[(quad * 4 + i) * 24 + m] = hb;            // LDS transpose (wave-lockstep)
            if (!IS_DEC) { if (endv[n] == t) sta2(hf_bf + (size_t)n * LL + jcol, hb); }
        }
        // coalesced 16B n-major stores: lanes 0..31 each store 8 bf16
        if (lane < 32) {
            const int nl = lane >> 1, jh = lane & 1;
            bf16x8 vv = *(const bf16x8*)&tr[nl * 24 + jh * 8];
            sta16(ho_bf + (size_t)(ng0 + nh * 16 + nl) * LL + jb + jh * 8, vv);
        }
    }
}

// ---------------------------------------------------------------- reparametrize tile -> hold regs + bf16
__device__ void emb_tile(const PParams& P, const int ng0, const int jb, const int tid,
                         f32x4 (&red)[2][4][64], unsigned short* hstage, f32x4& hold)
{
    const int lane = tid & 63, w = tid >> 6;
    const int nh = w & 1, kh = w >> 1;
    const int m = lane & 15, quad = lane >> 4;
    const int jcol = jb + m;

    stage_h32(P.hf_bf, ng0, hstage, tid);
    __syncthreads();

    f32x4 accm{}, accl{};
    const int arow = (nh * 16 + m) * HRS + quad * 8;
    const unsigned short* bmp = P.mlW_b + (size_t)jcol * LL + quad * 8;
    const unsigned short* blp = P.mlW_b + (size_t)(LL + jcol) * LL + quad * 8;
    #pragma unroll 4
    for (int c = kh * 16; c < kh * 16 + 16; ++c) {
        const int k0 = c * 32;
        bf16x8 av = *(const bf16x8*)&hstage[arow + k0];
        bf16x8 bm = *(const bf16x8*)(bmp + k0);
        bf16x8 bl = *(const bf16x8*)(blp + k0);
        accm = __builtin_amdgcn_mfma_f32_16x16x32_bf16(av, bm, accm, 0, 0, 0);
        accl = __builtin_amdgcn_mfma_f32_16x16x32_bf16(av, bl, accl, 0, 0, 0);
    }
    if (kh == 1) { red[nh][0][lane] = accm; red[nh][1][lane] = accl; }
    __syncthreads();
    if (kh == 0) {
        accm += red[nh][0][lane]; accl += red[nh][1][lane];
        unsigned short* tr = hstage + nh * (16 * 24);
        #pragma unroll
        for (int i = 0; i < 4; ++i) {
            const int n = ng0 + nh * 16 + quad * 4 + i;
            float mu = accm[i] + P.mub[jcol];
            float lv = accl[i] + P.lvb[jcol];
            float e = mu + expf(0.5f * lv) * P.eps[(size_t)n * LL + jcol];
            hold[i] = e;
            tr[(quad * 4 + i) * 24 + m] = f2bf(e);
        }
        if (lane < 32) {
            const int nl = lane >> 1, jh = lane & 1;
            bf16x8 vv = *(const bf16x8*)&tr[nl * 24 + jh * 8];
            sta16(P.hdecAb + (size_t)(ng0 + nh * 16 + nl) * LL + jb + jh * 8, vv);
        }
    }
}

// ---------------------------------------------------------------- MFMA decoder head: 16 samples/block
__device__ void head_tile(const PParams& P, const int n0, const int tid,
                          const unsigned short* __restrict__ h_bf, int ti,
                          unsigned short* hstage, char* shu)
{
    auto& ylds  = *(unsigned short (*)[16][136])(shu);
    auto& y2lds = *(unsigned short (*)[16][72])(shu + 4352);
    float* lred = (float*)(shu + 4352 + 2304);
    const int lane = tid & 63, w = tid >> 6;
    const int m16 = lane & 15, quad = lane >> 4;

    stage_h16(h_bf, n0, hstage, tid);
    __syncthreads();

    // ---- y1: K=1024, 8 j-tiles, wave w -> {2w, 2w+1}
    #pragma unroll
    for (int jt = 0; jt < 2; ++jt) {
        const int c0 = (w * 2 + jt) * 16;
        f32x4 acc{};
        const int abase = m16 * HRS + quad * 8;
        const unsigned short* bp = P.d1Wb + (size_t)(c0 + m16) * LL + quad * 8;
        #pragma unroll 4
        for (int c = 0; c < 32; ++c) {
            bf16x8 av = *(const bf16x8*)&hstage[abase + c * 32];
            bf16x8 bv = *(const bf16x8*)(bp + c * 32);
            acc = __builtin_amdgcn_mfma_f32_16x16x32_bf16(av, bv, acc, 0, 0, 0);
        }
        const float b = P.d1b[c0 + m16];
        #pragma unroll
        for (int i = 0; i < 4; ++i)
            ylds[quad * 4 + i][c0 + m16] = f2bf(fmaxf(acc[i] + b, 0.0f));
    }
    __syncthreads();

    // ---- y2: K=128, wave w -> tile w
    {
        const int c0 = w * 16;
        f32x4 acc{};
        #pragma unroll
        for (int c = 0; c < 4; ++c) {
            bf16x8 av = *(const bf16x8*)&ylds[m16][c * 32 + quad * 8];
            bf16x8 bv = *(const bf16x8*)(P.d2Wb + (size_t)(c0 + m16) * 128 + c * 32 + quad * 8);
            acc = __builtin_amdgcn_mfma_f32_16x16x32_bf16(av, bv, acc, 0, 0, 0);
        }
        const float b = P.d2b[c0 + m16];
        #pragma unroll
        for (int i = 0; i < 4; ++i)
            y2lds[quad * 4 + i][c0 + m16] = f2bf(fmaxf(acc[i] + b, 0.0f));
    }
    __syncthreads();

    // ---- y3: K=64, wave w -> {2w, 2w+1}; fused masked L1
    float lsum = 0.0f;
    #pragma unroll
    for (int jt = 0; jt < 2; ++jt) {
        const int c0 = (w * 2 + jt) * 16;
        f32x4 acc{};
        #pragma unroll
        for (int c = 0; c < 2; ++c) {
            bf16x8 av = *(const bf16x8*)&y2lds[m16][c * 32 + quad * 8];
            bf16x8 bv = *(const bf16x8*)(P.d3Wb + (size_t)(c0 + m16) * 64 + c * 32 + quad * 8);
            acc = __builtin_amdgcn_mfma_f32_16x16x32_bf16(av, bv, acc, 0, 0, 0);
        }
        const int col = c0 + m16;
        const float b = P.d3b[col];
        #pragma unroll
        for (int i = 0; i < 4; ++i) {
            const int n = n0 + quad * 4 + i;
            if (ti < P.limitv[n]) {
                int tr = ti + P.startv[n]; if (tr >= TT) tr -= TT;
                float v = P.s_next[(size_t)n * TT * SS + (size_t)tr * SS + col];
                lsum += fabsf(v - (acc[i] + b));
            }
        }
    }
    for (int off = 32; off >= 1; off >>= 1) lsum += __shfl_down(lsum, off);
    if (lane == 0) lred[w] = lsum;
    __syncthreads();
    if (tid == 0) atomicAdd(P.loss, lred[0] + lred[1] + lred[2] + lred[3]);
}

// ---------------------------------------------------------------- the persistent kernel
__global__ __launch_bounds__(256, 2)
void persist(PParams P)
{
    __shared__ __align__(16) unsigned short hstage[32 * HRS];   // 66176 B
    __shared__ __align__(16) char shu[8192];                    // red OR head ylds/y2lds/lred
    __shared__ int mint, sME, sML;
    f32x4 (&red)[2][4][64] = *(f32x4 (*)[2][4][64])(shu);
    const int bid = blockIdx.x, tid = threadIdx.x;
    const int g = bid & 3, lbid = bid >> 2;    // XCD-disjoint groups: g on XCDs {g, g+4}
    const int ng0 = g * 32;                    // group's first sample
    const int jb  = lbid * 16;                 // matmul blocks only (lbid < 64)
    int* gb = P.bar + 4608 + g * 128;          // group barrier state (512 B apart)
    int* broken = P.bar + 132;

    // ================= phase 0: cast (plain stores), split detection, h0, adec
    {
        const long N0 = 3072L * 160, N1 = N0 + 3072L * 1024, N2 = N1 + 3072L * 32,
                   N3 = N2 + 3072L * 1024, N4 = N3 + 1048576L, N5 = N4 + 1048576L,
                   N6 = N5 + 128L * 100 * 160, N7 = N6 + 131072L, N8 = N7 + 8192L,
                   N9 = N8 + 8192L;
        for (long i = (long)bid * 256 + tid; i < N9; i += (long)NBLK * 256) {
            if (i < N0)      P.eWih_b[i]      = f2bf(P.eWih[i]);
            else if (i < N1) P.eWhh_b[i - N0] = f2bf(P.eWhh[i - N0]);
            else if (i < N2) P.dWih_b[i - N1] = f2bf(P.dWih[i - N1]);
            else if (i < N3) P.dWhh_b[i - N2] = f2bf(P.dWhh[i - N2]);
            else if (i < N4) P.mlW_b[i - N3]  = f2bf(P.muW[i - N3]);
            else if (i < N5) P.mlW_b[1048576L + (i - N4)] = f2bf(P.lvW[i - N4]);
            else if (i < N6) {
                long j = i - N5;                  // n*16000 + t*160 + k
                int  k = (int)(j % 160);
                long nt = j / 160;
                int  t = (int)(nt % 100), n = (int)(nt / 100);
                float v = (k < SS) ? P.s[(size_t)n * TT * SS + (size_t)t * SS + k]
                                   : P.a[(size_t)n * TT * AA + (size_t)t * AA + (k - SS)];
                P.xenc_b[j] = f2bf(v);
            }
            else if (i < N7) P.d1Wb[i - N6] = f2bf(P.d1W[i - N6]);
            else if (i < N8) P.d2Wb[i - N7] = f2bf(P.d2W[i - N7]);
            else             P.d3Wb[i - N8] = f2bf(P.d3W[i - N8]);
        }
    }
    if (bid < NN_) {
        const int n = bid;
        if (tid == 0) mint = TT - 1;
        __syncthreads();
        int t = tid + 1;
        if (t < TT && tid < 128) {
            const float* row = P.s + (size_t)n * TT * SS + (size_t)t * SS;
            bool allz = true;
            for (int i = 0; i < SS; ++i) { if (row[i] != 0.0f) { allz = false; break; } }
            if (allz) atomicMin(&mint, t);
        }
        __syncthreads();
        const int m = mint, st = m + 1;
        if (tid == 0) { P.endv[n] = m - 1; P.startv[n] = st; P.limitv[n] = TT - 1 - m; }
        for (int idx = tid; idx < LL; idx += 256)
            P.hencAb[(size_t)n * LL + idx] = 0x3F80;   // bf16 1.0
        for (int idx = tid; idx < 50 * AA; idx += 256) {
            int i = idx >> 5, k = idx & 31;
            int tr = i + st; if (tr >= TT) tr -= TT;
            P.adec_b[(size_t)n * (50 * AA) + idx] =
                f2bf(P.a[(size_t)n * TT * AA + (size_t)tr * AA + k]);
        }
    }
    // one-time global heavy barrier: flush phase-0 plain stores, drop stale lines
    __syncthreads();
    if (tid == 0) __threadfence();
    gbar_global(P.bar, bid, tid, 1);
    if (tid == 0) __threadfence();
    __syncthreads();

    // ================= group-local ME = max(end), ML = max(limit) over 32 samples
    int ME, ML;
    {
        int lv = 0, ev = 0;
        if (tid < 32) { lv = P.limitv[ng0 + tid]; ev = P.endv[ng0 + tid]; }
        if (tid < 64) {
            for (int off = 16; off >= 1; off >>= 1) {
                lv = max(lv, __shfl_down(lv, off));
                ev = max(ev, __shfl_down(ev, off));
            }
            if (tid == 0) { sML = lv; sME = ev; }
        }
        __syncthreads();
        ML = sML; ME = sME;
        __syncthreads();
    }

    f32x4 hold = { 1.0f, 1.0f, 1.0f, 1.0f };   // enc h0 = ones (fp32 state lives here)
    int ggen = 0;

    // ================= encoder: t = 0..ME_g
    for (int t = 0; t <= ME; ++t) {
        if (lbid < 64) {
            const unsigned short* hib = (t & 1) ? P.hencBb : P.hencAb;
            unsigned short*       hob = (t & 1) ? P.hencAb : P.hencBb;
            gru_tile<160, false>(ng0, jb, tid, hib, hob,
                                 P.eWhh_b, P.eWih_b, P.xenc_b, P.ebih, P.ebhh,
                                 P.endv, P.hf_bf, t, red, hstage, hold);
        }
        gbar_group(gb, broken, lbid, tid, ++ggen);
    }

    // ================= reparametrize (deposits decoder h0 into hold regs)
    if (lbid < 64) emb_tile(P, ng0, jb, tid, red, hstage, hold);
    gbar_group(gb, broken, lbid, tid, ++ggen);

    // ================= decoder: i = 0..ML_g; matmul (i<ML) overlaps head for step i-1
    for (int i = 0; i <= ML; ++i) {
        const unsigned short* hib = (i & 1) ? P.hdecBb : P.hdecAb;
        if (lbid < 64) {
            if (i < ML) {
                unsigned short* hob = (i & 1) ? P.hdecAb : P.hdecBb;
                gru_tile<32, true>(ng0, jb, tid, hib, hob,
                                   P.dWhh_b, P.dWih_b, P.adec_b, P.dbih, P.dbhh,
                                   nullptr, nullptr, i, red, hstage, hold);
            }
        } else if (i >= 1) {
            head_tile(P, ng0 + (lbid - 64) * 16, tid, hib, i - 1, hstage, shu);
        }
        gbar_group(gb, broken, lbid, tid, ++ggen);
    }
}

// ---------------------------------------------------------------- launch
extern "C" void kernel_launch(void* const* d_in, const int* in_sizes, int n_in,
                              void* d_out, int out_size, void* d_ws, size_t ws_size,
                              hipStream_t stream) {
    PParams P;
    P.s      = (const float*)d_in[0];
    P.a      = (const float*)d_in[1];
    P.s_next = (const float*)d_in[3];
    P.eps    = (const float*)d_in[4];
    P.eWih   = (const float*)d_in[5];
    P.eWhh   = (const float*)d_in[6];
    P.ebih   = (const float*)d_in[7];
    P.ebhh   = (const float*)d_in[8];
    P.muW    = (const float*)d_in[9];
    P.mub    = (const float*)d_in[10];
    P.lvW    = (const float*)d_in[11];
    P.lvb    = (const float*)d_in[12];
    // st1..st3 (13..18) dead code w.r.t. the loss
    P.dWih   = (const float*)d_in[19];
    P.dWhh   = (const float*)d_in[20];
    P.dbih   = (const float*)d_in[21];
    P.dbhh   = (const float*)d_in[22];
    P.d1W    = (const float*)d_in[23];
    P.d1b    = (const float*)d_in[24];
    P.d2W    = (const float*)d_in[25];
    P.d2b    = (const float*)d_in[26];
    P.d3W    = (const float*)d_in[27];
    P.d3b    = (const float*)d_in[28];
    P.loss   = (float*)d_out;

    char* p = (char*)d_ws;
    P.bar    = (int*)p;                    p += 20480;
    P.endv   = (int*)p;                    p += 512;
    P.startv = (int*)p;                    p += 512;
    P.limitv = (int*)p;                    p += 512;
    p += 2560;                             // pad
    P.hencAb = (unsigned short*)p;         p += 128 * 1024 * 2;
    P.hencBb = (unsigned short*)p;         p += 128 * 1024 * 2;
    P.hdecAb = (unsigned short*)p;         p += 128 * 1024 * 2;
    P.hdecBb = (unsigned short*)p;         p += 128 * 1024 * 2;
    P.hf_bf  = (unsigned short*)p;         p += 128 * 1024 * 2;
    P.eWih_b = (unsigned short*)p;         p += 3072 * 160 * 2;
    P.eWhh_b = (unsigned short*)p;         p += 3072 * 1024 * 2;
    P.dWih_b = (unsigned short*)p;         p += 3072 * 32 * 2;
    P.dWhh_b = (unsigned short*)p;         p += 3072 * 1024 * 2;
    P.mlW_b  = (unsigned short*)p;         p += 2048 * 1024 * 2;
    P.xenc_b = (unsigned short*)p;         p += 128 * 100 * 160 * 2;
    P.adec_b = (unsigned short*)p;         p += 128 * 50 * 32 * 2;
    P.d1Wb   = (unsigned short*)p;         p += 128 * 1024 * 2;
    P.d2Wb   = (unsigned short*)p;         p += 64 * 128 * 2;
    P.d3Wb   = (unsigned short*)p;         p += 128 * 64 * 2;

    hipLaunchKernelGGL(init_kernel, dim3(1), dim3(256), 0, stream, P.bar, P.loss);
    hipLaunchKernelGGL(persist, dim3(NBLK), dim3(256), 0, stream, P);
}